// Round 1
// baseline (182.710 us; speedup 1.0000x reference)
//
#include <hip/hip_runtime.h>
#include <math.h>

#define BB 32
#define TT 2048
#define DD 1024   // HID == OUT == DV == 1024
#define HF 512    // OUT/2

// ---------------------------------------------------------------------------
// fast tanh: 1 - 2/(exp(2x)+1).  Saturates correctly for |x| large.
__device__ __forceinline__ float tanh_fast(float x) {
    float e = __expf(2.0f * x);
    return 1.0f - 2.0f / (e + 1.0f);
}

// ---------------------------------------------------------------------------
// w[d] = sum_j W1[d,j] * W2[j];  c = sum_j b1[j]*W2[j] + b2
__global__ void __launch_bounds__(256) prep_w_kernel(
        const float* __restrict__ W1, const float* __restrict__ b1,
        const float* __restrict__ W2, const float* __restrict__ b2,
        float* __restrict__ w, float* __restrict__ cbias) {
    int d = blockIdx.x * 256 + threadIdx.x;   // grid 4 x 256
    const float* row = W1 + (size_t)d * HF;
    float acc = 0.0f;
    for (int j = 0; j < HF; j += 4) {
        float4 a = *(const float4*)(row + j);
        float4 b = *(const float4*)(W2 + j);
        acc += a.x * b.x + a.y * b.y + a.z * b.z + a.w * b.w;
    }
    w[d] = acc;
    if (blockIdx.x == 0 && threadIdx.x == 0) {
        float s = 0.0f;
        for (int j = 0; j < HF; ++j) s += b1[j] * W2[j];
        cbias[0] = s + b2[0];
    }
}

// ---------------------------------------------------------------------------
// query[b,o] = sum_h hidden[b,h] * Wq[h,o] + bq[o]
// grid (OUT/256, B/8); each block: 8 batch rows, 256 output cols
__global__ void __launch_bounds__(256) query_kernel(
        const float* __restrict__ hidden, const float* __restrict__ Wq,
        const float* __restrict__ bq, float* __restrict__ query) {
    int o  = blockIdx.x * 256 + threadIdx.x;
    int b0 = blockIdx.y * 8;
    __shared__ float hs[8][DD];
    for (int idx = threadIdx.x; idx < 8 * (DD / 4); idx += 256) {
        int r  = idx >> 8;            // DD/4 == 256
        int h4 = (idx & 255) << 2;
        *(float4*)&hs[r][h4] = *(const float4*)&hidden[(size_t)(b0 + r) * DD + h4];
    }
    __syncthreads();
    float acc[8] = {0, 0, 0, 0, 0, 0, 0, 0};
    for (int h = 0; h < DD; h += 4) {
        float w0 = Wq[(size_t)(h    ) * DD + o];
        float w1 = Wq[(size_t)(h + 1) * DD + o];
        float w2 = Wq[(size_t)(h + 2) * DD + o];
        float w3 = Wq[(size_t)(h + 3) * DD + o];
        #pragma unroll
        for (int r = 0; r < 8; ++r) {
            float4 hv = *(const float4*)&hs[r][h];
            acc[r] = fmaf(hv.w, w3, fmaf(hv.z, w2, fmaf(hv.y, w1, fmaf(hv.x, w0, acc[r]))));
        }
    }
    float bb = bq[o];
    #pragma unroll
    for (int r = 0; r < 8; ++r)
        query[(size_t)(b0 + r) * DD + o] = acc[r] + bb;
}

// ---------------------------------------------------------------------------
// scores[b,t] = c + sum_d tanh(key[b,t,d] + query[b,d]) * w[d]
// grid (T/4, B); block 256 = 4 waves; wave i handles t = blockIdx.x*4 + i.
// Rows with t >= seq_len are skipped entirely (softmax masks them).
__global__ void __launch_bounds__(256) scores_kernel(
        const float* __restrict__ key, const float* __restrict__ query,
        const float* __restrict__ w, const float* __restrict__ cb,
        const int* __restrict__ seq_lens, float* __restrict__ scores) {
    int b   = blockIdx.y;
    int len = seq_lens[b];
    int t0  = blockIdx.x * 4;
    if (t0 >= len) return;                      // uniform exit: whole block masked

    __shared__ float wsh[DD];
    __shared__ float qsh[DD];
    for (int idx = threadIdx.x; idx < DD / 4; idx += 256) {
        *(float4*)&wsh[idx * 4] = *(const float4*)&w[idx * 4];
        *(float4*)&qsh[idx * 4] = *(const float4*)&query[(size_t)b * DD + idx * 4];
    }
    __syncthreads();

    int wave = threadIdx.x >> 6;
    int lane = threadIdx.x & 63;
    int t = t0 + wave;
    if (t >= len) return;                       // no barriers after this point

    const float* krow = key + ((size_t)(b * TT + t)) * DD;
    float acc = 0.0f;
    #pragma unroll
    for (int kblk = 0; kblk < 4; ++kblk) {
        int d = kblk * 256 + lane * 4;
        float4 kv = *(const float4*)(krow + d);
        float4 qv = *(const float4*)&qsh[d];
        float4 wv = *(const float4*)&wsh[d];
        acc += tanh_fast(kv.x + qv.x) * wv.x;
        acc += tanh_fast(kv.y + qv.y) * wv.y;
        acc += tanh_fast(kv.z + qv.z) * wv.z;
        acc += tanh_fast(kv.w + qv.w) * wv.w;
    }
    #pragma unroll
    for (int off = 32; off; off >>= 1) acc += __shfl_down(acc, off);
    if (lane == 0) scores[(size_t)b * TT + t] = acc + cb[0];
}

// ---------------------------------------------------------------------------
// masked softmax over T per batch row; writes attn (zeros past len) to d_out
__global__ void __launch_bounds__(256) softmax_kernel(
        const float* __restrict__ scores, const int* __restrict__ seq_lens,
        float* __restrict__ attn) {
    int b   = blockIdx.x;
    int len = seq_lens[b];
    int wave = threadIdx.x >> 6, lane = threadIdx.x & 63;

    float v[8];
    float mx = -INFINITY;
    #pragma unroll
    for (int i = 0; i < 8; ++i) {
        int t = i * 256 + threadIdx.x;
        float s = (t < len) ? scores[(size_t)b * TT + t] : -INFINITY;
        v[i] = s;
        mx = fmaxf(mx, s);
    }
    #pragma unroll
    for (int off = 32; off; off >>= 1) mx = fmaxf(mx, __shfl_down(mx, off));
    __shared__ float sm[4];
    if (lane == 0) sm[wave] = mx;
    __syncthreads();
    mx = fmaxf(fmaxf(sm[0], sm[1]), fmaxf(sm[2], sm[3]));

    float e[8];
    float sum = 0.0f;
    #pragma unroll
    for (int i = 0; i < 8; ++i) {
        int t = i * 256 + threadIdx.x;
        float p = (t < len) ? __expf(v[i] - mx) : 0.0f;
        e[i] = p;
        sum += p;
    }
    #pragma unroll
    for (int off = 32; off; off >>= 1) sum += __shfl_down(sum, off);
    __shared__ float ss[4];
    if (lane == 0) ss[wave] = sum;
    __syncthreads();
    sum = ss[0] + ss[1] + ss[2] + ss[3];

    float inv = 1.0f / sum;
    #pragma unroll
    for (int i = 0; i < 8; ++i) {
        int t = i * 256 + threadIdx.x;
        attn[(size_t)b * TT + t] = e[i] * inv;
    }
}

// ---------------------------------------------------------------------------
// partial[b,tch,:] = sum_{t in chunk, t<len} attn[b,t] * value[b,t,:]
// grid (TCH=16, B); block 256; each thread owns 4 consecutive d (float4)
#define TCH 16
#define TCHUNK (TT / TCH)   // 128
__global__ void __launch_bounds__(256) context_partial_kernel(
        const float* __restrict__ value, const float* __restrict__ attn,
        const int* __restrict__ seq_lens, float* __restrict__ partial) {
    int tch = blockIdx.x;
    int b   = blockIdx.y;
    int len = seq_lens[b];
    int t0  = tch * TCHUNK;
    int d4  = threadIdx.x * 4;
    float4 acc = {0.0f, 0.0f, 0.0f, 0.0f};
    int tend = min(t0 + TCHUNK, len);
    const float* vbase = value + (size_t)b * TT * DD + d4;
    for (int t = t0; t < tend; ++t) {
        float a = attn[(size_t)b * TT + t];
        float4 vv = *(const float4*)(vbase + (size_t)t * DD);
        acc.x = fmaf(a, vv.x, acc.x);
        acc.y = fmaf(a, vv.y, acc.y);
        acc.z = fmaf(a, vv.z, acc.z);
        acc.w = fmaf(a, vv.w, acc.w);
    }
    *(float4*)&partial[((size_t)(b * TCH + tch)) * DD + d4] = acc;
}

// ---------------------------------------------------------------------------
// ctx[b,d] = sum_tch partial[b,tch,d]
__global__ void __launch_bounds__(256) context_reduce_kernel(
        const float* __restrict__ partial, float* __restrict__ ctx) {
    int d = blockIdx.x * 256 + threadIdx.x;   // grid (4, 32)
    int b = blockIdx.y;
    float acc = 0.0f;
    #pragma unroll
    for (int c = 0; c < TCH; ++c)
        acc += partial[((size_t)(b * TCH + c)) * DD + d];
    ctx[(size_t)b * DD + d] = acc;
}

// ---------------------------------------------------------------------------
extern "C" void kernel_launch(void* const* d_in, const int* in_sizes, int n_in,
                              void* d_out, int out_size, void* d_ws, size_t ws_size,
                              hipStream_t stream) {
    const float* hidden   = (const float*)d_in[0];
    const float* key      = (const float*)d_in[1];
    const float* value    = (const float*)d_in[2];
    const int*   seq_lens = (const int*)  d_in[3];
    const float* Wq       = (const float*)d_in[4];
    const float* bq       = (const float*)d_in[5];
    const float* W1       = (const float*)d_in[6];
    const float* b1       = (const float*)d_in[7];
    const float* W2       = (const float*)d_in[8];
    const float* b2       = (const float*)d_in[9];

    float* out  = (float*)d_out;
    float* ctx  = out;                 // [32*1024]
    float* attn = out + BB * DD;       // [32*2048]

    float* ws      = (float*)d_ws;
    float* w       = ws;               // 1024
    float* cb      = ws + 1024;        // 1
    float* query   = ws + 2048;        // 32768
    float* scores  = ws + 2048 + BB * DD;            // 65536
    float* partial = scores + BB * TT;               // 32*16*1024 = 524288

    prep_w_kernel<<<dim3(DD / 256), dim3(256), 0, stream>>>(W1, b1, W2, b2, w, cb);
    query_kernel<<<dim3(DD / 256, BB / 8), dim3(256), 0, stream>>>(hidden, Wq, bq, query);
    scores_kernel<<<dim3(TT / 4, BB), dim3(256), 0, stream>>>(key, query, w, cb, seq_lens, scores);
    softmax_kernel<<<dim3(BB), dim3(256), 0, stream>>>(scores, seq_lens, attn);
    context_partial_kernel<<<dim3(TCH, BB), dim3(256), 0, stream>>>(value, attn, seq_lens, partial);
    context_reduce_kernel<<<dim3(DD / 256, BB), dim3(256), 0, stream>>>(partial, ctx);
}

// Round 2
// 103.431 us; speedup vs baseline: 1.7665x; 1.7665x over previous
//
#include <hip/hip_runtime.h>
#include <math.h>

#define BB 32
#define TT 2048
#define DD 1024   // HID == OUT == DV == 1024
#define HF 512    // OUT/2

#define QKS 32            // k-split chunks for query projection
#define QCH (DD / QKS)    // 32 h per chunk

#define TCH 64            // t-chunks for context
#define TCHUNK (TT / TCH) // 32 rows per chunk

// ---------------------------------------------------------------------------
__device__ __forceinline__ float tanh_fast(float x) {
    float e = __expf(2.0f * x);
    return 1.0f - 2.0f / (e + 1.0f);
}

// ---------------------------------------------------------------------------
// Fused role kernel (all independent preprocessing in one launch):
//   blocks 0..3   : w[d] = sum_j W1[d,j]*W2[j]            (d = bx*256+tid)
//   block  4      : cbias = sum_j b1[j]*W2[j] + b2
//   blocks 5..132 : query partials, qpart[ks][b][o] = sum_{h in chunk ks} hidden[b,h]*Wq[h,o]
__global__ void __launch_bounds__(256) prep_query_kernel(
        const float* __restrict__ hidden, const float* __restrict__ Wq,
        const float* __restrict__ W1, const float* __restrict__ b1,
        const float* __restrict__ W2, const float* __restrict__ b2,
        float* __restrict__ w, float* __restrict__ cbias,
        float* __restrict__ qpart) {
    __shared__ float hs[BB][QCH];   // 4 KB (query role)
    __shared__ float red[256];      // 1 KB (cbias role)
    int bx  = blockIdx.x;
    int tid = threadIdx.x;

    if (bx < 4) {                                   // ---- w = W1 @ W2
        int d = bx * 256 + tid;
        const float* row = W1 + (size_t)d * HF;
        float acc = 0.0f;
        #pragma unroll 4
        for (int j = 0; j < HF; j += 4) {
            float4 a = *(const float4*)(row + j);
            float4 b = *(const float4*)(W2 + j);
            acc += a.x * b.x + a.y * b.y + a.z * b.z + a.w * b.w;
        }
        w[d] = acc;
        return;
    }
    if (bx == 4) {                                  // ---- cbias
        float s = b1[tid] * W2[tid] + b1[tid + 256] * W2[tid + 256];
        red[tid] = s;
        __syncthreads();
        for (int off = 128; off; off >>= 1) {
            if (tid < off) red[tid] += red[tid + off];
            __syncthreads();
        }
        if (tid == 0) cbias[0] = red[0] + b2[0];
        return;
    }
    // ---- query partial: idx -> (otile, ks)
    int idx   = bx - 5;
    int otile = idx & 3;
    int ks    = idx >> 2;
    int o     = otile * 256 + tid;
    int h0    = ks * QCH;

    // stage hidden[0:32, h0:h0+QCH] (1024 floats; one float4 per thread)
    {
        int r  = tid >> 3;              // QCH/4 == 8 float4 per row
        int c4 = (tid & 7) << 2;
        *(float4*)&hs[r][c4] = *(const float4*)&hidden[(size_t)r * DD + h0 + c4];
    }
    __syncthreads();

    float acc[BB];
    #pragma unroll
    for (int b = 0; b < BB; ++b) acc[b] = 0.0f;

    #pragma unroll 4
    for (int h = 0; h < QCH; ++h) {
        float wv = Wq[(size_t)(h0 + h) * DD + o];
        #pragma unroll
        for (int b = 0; b < BB; ++b)
            acc[b] = fmaf(hs[b][h], wv, acc[b]);
    }
    #pragma unroll
    for (int b = 0; b < BB; ++b)
        qpart[((size_t)ks * BB + b) * DD + o] = acc[b];
}

// ---------------------------------------------------------------------------
// query[b,o] = bq[o] + sum_ks qpart[ks][b][o]
__global__ void __launch_bounds__(256) qreduce_kernel(
        const float* __restrict__ qpart, const float* __restrict__ bq,
        float* __restrict__ query) {
    int i = blockIdx.x * 256 + threadIdx.x;   // grid 128: i in [0, BB*DD)
    int o = i & (DD - 1);
    float acc = bq[o];
    #pragma unroll
    for (int ks = 0; ks < QKS; ++ks)
        acc += qpart[(size_t)ks * (BB * DD) + i];
    query[i] = acc;
}

// ---------------------------------------------------------------------------
// scores[b,t] = c + sum_d tanh(key[b,t,d] + query[b,d]) * w[d]
// grid (T/16, B); block 256 = 4 waves; 16 t-rows per block (4 per wave).
__global__ void __launch_bounds__(256) scores_kernel(
        const float* __restrict__ key, const float* __restrict__ query,
        const float* __restrict__ w, const float* __restrict__ cb,
        const int* __restrict__ seq_lens, float* __restrict__ scores) {
    int b   = blockIdx.y;
    int len = seq_lens[b];
    int t0  = blockIdx.x * 16;
    if (t0 >= len) return;                      // uniform: whole block masked

    __shared__ float wsh[DD];
    __shared__ float qsh[DD];
    {
        int i4 = threadIdx.x * 4;               // 256 threads x float4 = 1024
        *(float4*)&wsh[i4] = *(const float4*)&w[i4];
        *(float4*)&qsh[i4] = *(const float4*)&query[(size_t)b * DD + i4];
    }
    __syncthreads();

    int wave = threadIdx.x >> 6;
    int lane = threadIdx.x & 63;
    float c0 = cb[0];

    #pragma unroll
    for (int tt = 0; tt < 4; ++tt) {
        int t = t0 + tt * 4 + wave;
        if (t >= len) break;                    // t monotone in tt
        const float* krow = key + ((size_t)(b * TT + t)) * DD;
        float acc = 0.0f;
        #pragma unroll
        for (int kblk = 0; kblk < 4; ++kblk) {
            int d = kblk * 256 + lane * 4;
            float4 kv = *(const float4*)(krow + d);
            float4 qv = *(const float4*)&qsh[d];
            float4 wv = *(const float4*)&wsh[d];
            acc += tanh_fast(kv.x + qv.x) * wv.x;
            acc += tanh_fast(kv.y + qv.y) * wv.y;
            acc += tanh_fast(kv.z + qv.z) * wv.z;
            acc += tanh_fast(kv.w + qv.w) * wv.w;
        }
        #pragma unroll
        for (int off = 32; off; off >>= 1) acc += __shfl_down(acc, off);
        if (lane == 0) scores[(size_t)b * TT + t] = acc + c0;
    }
}

// ---------------------------------------------------------------------------
// masked softmax over T per batch row; writes attn (zeros past len) to d_out
__global__ void __launch_bounds__(256) softmax_kernel(
        const float* __restrict__ scores, const int* __restrict__ seq_lens,
        float* __restrict__ attn) {
    int b   = blockIdx.x;
    int len = seq_lens[b];
    int wave = threadIdx.x >> 6, lane = threadIdx.x & 63;

    float v[8];
    float mx = -INFINITY;
    #pragma unroll
    for (int i = 0; i < 8; ++i) {
        int t = i * 256 + threadIdx.x;
        float s = (t < len) ? scores[(size_t)b * TT + t] : -INFINITY;
        v[i] = s;
        mx = fmaxf(mx, s);
    }
    #pragma unroll
    for (int off = 32; off; off >>= 1) mx = fmaxf(mx, __shfl_down(mx, off));
    __shared__ float sm[4];
    if (lane == 0) sm[wave] = mx;
    __syncthreads();
    mx = fmaxf(fmaxf(sm[0], sm[1]), fmaxf(sm[2], sm[3]));

    float e[8];
    float sum = 0.0f;
    #pragma unroll
    for (int i = 0; i < 8; ++i) {
        int t = i * 256 + threadIdx.x;
        float p = (t < len) ? __expf(v[i] - mx) : 0.0f;
        e[i] = p;
        sum += p;
    }
    #pragma unroll
    for (int off = 32; off; off >>= 1) sum += __shfl_down(sum, off);
    __shared__ float ss[4];
    if (lane == 0) ss[wave] = sum;
    __syncthreads();
    sum = ss[0] + ss[1] + ss[2] + ss[3];

    float inv = 1.0f / sum;
    #pragma unroll
    for (int i = 0; i < 8; ++i) {
        int t = i * 256 + threadIdx.x;
        attn[(size_t)b * TT + t] = e[i] * inv;
    }
}

// ---------------------------------------------------------------------------
// partial[b,tch,:] = sum_{t in chunk, t<len} attn[b,t] * value[b,t,:]
// grid (TCH, B); chunks entirely past len are skipped (reduce won't read them)
__global__ void __launch_bounds__(256) context_partial_kernel(
        const float* __restrict__ value, const float* __restrict__ attn,
        const int* __restrict__ seq_lens, float* __restrict__ partial) {
    int tch = blockIdx.x;
    int b   = blockIdx.y;
    int len = seq_lens[b];
    int t0  = tch * TCHUNK;
    if (t0 >= len) return;                      // masked chunk: never read
    int d4  = threadIdx.x * 4;
    float4 acc = {0.0f, 0.0f, 0.0f, 0.0f};
    int tend = min(t0 + TCHUNK, len);
    const float* vbase = value + (size_t)b * TT * DD + d4;
    for (int t = t0; t < tend; ++t) {
        float a = attn[(size_t)b * TT + t];
        float4 vv = *(const float4*)(vbase + (size_t)t * DD);
        acc.x = fmaf(a, vv.x, acc.x);
        acc.y = fmaf(a, vv.y, acc.y);
        acc.z = fmaf(a, vv.z, acc.z);
        acc.w = fmaf(a, vv.w, acc.w);
    }
    *(float4*)&partial[((size_t)(b * TCH + tch)) * DD + d4] = acc;
}

// ---------------------------------------------------------------------------
// ctx[b,d] = sum over live chunks of partial[b,c,d]
__global__ void __launch_bounds__(256) context_reduce_kernel(
        const float* __restrict__ partial, const int* __restrict__ seq_lens,
        float* __restrict__ ctx) {
    int d = blockIdx.x * 256 + threadIdx.x;   // grid (4, 32)
    int b = blockIdx.y;
    int nch = min(TCH, (seq_lens[b] + TCHUNK - 1) / TCHUNK);
    float acc = 0.0f;
    for (int c = 0; c < nch; ++c)
        acc += partial[((size_t)(b * TCH + c)) * DD + d];
    ctx[(size_t)b * DD + d] = acc;
}

// ---------------------------------------------------------------------------
extern "C" void kernel_launch(void* const* d_in, const int* in_sizes, int n_in,
                              void* d_out, int out_size, void* d_ws, size_t ws_size,
                              hipStream_t stream) {
    const float* hidden   = (const float*)d_in[0];
    const float* key      = (const float*)d_in[1];
    const float* value    = (const float*)d_in[2];
    const int*   seq_lens = (const int*)  d_in[3];
    const float* Wq       = (const float*)d_in[4];
    const float* bq       = (const float*)d_in[5];
    const float* W1       = (const float*)d_in[6];
    const float* b1       = (const float*)d_in[7];
    const float* W2       = (const float*)d_in[8];
    const float* b2       = (const float*)d_in[9];

    float* out  = (float*)d_out;
    float* ctx  = out;                 // [32*1024]
    float* attn = out + BB * DD;       // [32*2048]

    float* ws      = (float*)d_ws;
    float* w       = ws;                               // 1024
    float* cb      = ws + 1024;                        // 1 (padded)
    float* query   = ws + 2048;                        // 32768
    float* qpart   = query + BB * DD;                  // 32*32*1024 = 1048576
    float* scores  = qpart + (size_t)QKS * BB * DD;    // 65536
    float* partial = scores + BB * TT;                 // 32*64*1024 = 2097152

    prep_query_kernel<<<dim3(5 + 4 * QKS), dim3(256), 0, stream>>>(
        hidden, Wq, W1, b1, W2, b2, w, cb, qpart);
    qreduce_kernel<<<dim3(BB * DD / 256), dim3(256), 0, stream>>>(qpart, bq, query);
    scores_kernel<<<dim3(TT / 16, BB), dim3(256), 0, stream>>>(key, query, w, cb, seq_lens, scores);
    softmax_kernel<<<dim3(BB), dim3(256), 0, stream>>>(scores, seq_lens, attn);
    context_partial_kernel<<<dim3(TCH, BB), dim3(256), 0, stream>>>(value, attn, seq_lens, partial);
    context_reduce_kernel<<<dim3(DD / 256, BB), dim3(256), 0, stream>>>(partial, seq_lens, ctx);
}